// Round 1
// baseline (3645.359 us; speedup 1.0000x reference)
//
#include <hip/hip_runtime.h>

#define NFEAT   39
#define SEQL    40
#define EDIM    128
#define NSTATE  16
#define NLAYERS 4
#define VROWS   10001   // VOCAB + 1

// ---------------- bf16 helpers (raw ushort storage) ----------------
__device__ __forceinline__ float b2f(unsigned short u) {
  unsigned v = ((unsigned)u) << 16;
  return __builtin_bit_cast(float, v);
}
__device__ __forceinline__ unsigned short f2b(float f) {
  unsigned u = __builtin_bit_cast(unsigned, f);
  u += 0x7FFFu + ((u >> 16) & 1u);   // round-to-nearest-even
  return (unsigned short)(u >> 16);
}
__device__ __forceinline__ void ld4(const unsigned short* p,
                                    float& a, float& b, float& c, float& d) {
  uint2 u = *(const uint2*)p;        // 4 consecutive bf16 (8B aligned)
  a = __builtin_bit_cast(float, u.x << 16);
  b = __builtin_bit_cast(float, u.x & 0xFFFF0000u);
  c = __builtin_bit_cast(float, u.y << 16);
  d = __builtin_bit_cast(float, u.y & 0xFFFF0000u);
}
// runtime-dtype input load (embedding table / cls path)
__device__ __forceinline__ float ldin(const void* p, long i, int bf) {
  if (bf) return b2f(((const unsigned short*)p)[i]);
  return ((const float*)p)[i];
}

// ---------------- weight conversion: anything -> f32 in d_ws ----------------
// 17 small tensors (inputs 2..18), laid out contiguously. Detects dtype from
// ln_g (all-ones): f32 word 0x3F800000 vs bf16 pair 0x3F803F80.
struct ConvArgs {
  const void* src[17];
  int off[18];              // off[k] = start of tensor k; off[17] = total
};

__global__ void convert_kernel(ConvArgs a, float* W, int* flag) {
  unsigned w0 = *(const unsigned*)a.src[1];          // ln_g first 4 bytes
  int bf = (w0 != 0x3F800000u) ? 1 : 0;
  if (blockIdx.x == 0 && threadIdx.x == 0) *flag = bf;
  int total = a.off[17];
  for (int i = blockIdx.x * blockDim.x + threadIdx.x; i < total;
       i += gridDim.x * blockDim.x) {
    int s = 0;
#pragma unroll
    for (int k = 1; k < 17; ++k) s = (i >= a.off[k]) ? k : s;
    int local = i - a.off[s];
    float v = bf ? b2f(((const unsigned short*)a.src[s])[local])
                 : ((const float*)a.src[s])[local];
    W[i] = v;
  }
}

// Static offsets (floats) into converted weight arena, matching conv order:
// cls, ln_g, ln_b, xproj_w, xproj_b, A, D, outproj_w, outproj_b,
// merge_w, merge_b, w1, b1, w2, b2, w3, b3
#define OFF_CLS 0
#define OFF_LNG 128
#define OFF_LNB 1152
#define OFF_XW  2176
#define OFF_XB  264320
#define OFF_A   266368
#define OFF_D   282752
#define OFF_OW  283776
#define OFF_OB  414848
#define OFF_MW  415872
#define OFF_MB  546944
#define OFF_W1  547456
#define OFF_B1  563840
#define OFF_W2  563968
#define OFF_B2  572160
#define OFF_W3  572224
#define OFF_B3  572288

// ---------------- main kernel: one block per sample ----------------
__global__ __launch_bounds__(256)
void mamba_kernel(const int* __restrict__ x, const void* __restrict__ emb,
                  const float* __restrict__ W, const int* __restrict__ flagp,
                  void* __restrict__ outp) {
  // LDS: residual stream f32 (precision), the rest bf16. Total 60 KB.
  __shared__ __align__(16) float          sCar[SEQL][EDIM];  // 20 KB
  __shared__ __align__(16) unsigned short sXn [SEQL][EDIM];  // 10 KB
  __shared__ __align__(16) unsigned short sH  [SEQL][EDIM];  // 10 KB  prod -> cumsum -> o
  __shared__ __align__(16) unsigned short sS  [SEQL][EDIM];  // 10 KB  s; later bk
  __shared__ __align__(16) unsigned short sF  [SEQL][EDIM];  // 10 KB  f

  const int b    = blockIdx.x;
  const int tid  = threadIdx.x;
  const int wave = tid >> 6;
  const int lane = tid & 63;
  const int bf   = *flagp;

  const float* cls = W + OFF_CLS;
  const float* lng = W + OFF_LNG;
  const float* lnb = W + OFF_LNB;
  const float* xw  = W + OFF_XW;
  const float* xb  = W + OFF_XB;
  const float* Aw  = W + OFF_A;
  const float* Dw  = W + OFF_D;
  const float* ow  = W + OFF_OW;
  const float* ob  = W + OFF_OB;
  const float* mw  = W + OFF_MW;
  const float* mbp = W + OFF_MB;
  const float* w1p = W + OFF_W1;
  const float* b1p = W + OFF_B1;
  const float* w2p = W + OFF_W2;
  const float* b2p = W + OFF_B2;
  const float* w3p = W + OFF_W3;
  const float* b3p = W + OFF_B3;

  // ---- build seq: cls at t=0, embedding gather (row 0 zeroed) for t>=1
  for (int i = tid; i < SEQL * EDIM; i += 256) {
    int t = i >> 7, e = i & 127;
    float v;
    if (t == 0) {
      v = cls[e];
    } else {
      int f = t - 1;
      int idx = x[b * NFEAT + f];
      if (idx == 0) v = 0.f;
      else          v = ldin(emb, ((long)f * VROWS + idx) * EDIM + e, bf);
    }
    sCar[t][e] = v;
  }
  __syncthreads();

  for (int l = 0; l < NLAYERS; ++l) {
    for (int dir = 0; dir < 2; ++dir) {
      const int    pd = l * 2 + dir;
      const float* g  = lng + pd * EDIM;
      const float* bb = lnb + pd * EDIM;
      const float* wx = xw  + pd * EDIM * 2 * EDIM;
      const float* bx = xb  + pd * 2 * EDIM;
      const float* Ap = Aw  + pd * EDIM * NSTATE;
      const float* Dp = Dw  + pd * EDIM;
      const float* wo = ow  + pd * EDIM * EDIM;
      const float* bo = ob  + pd * EDIM;

      // ---- LayerNorm: one wave per token, 2 channels per lane
      for (int t = wave; t < SEQL; t += 4) {
        float v0 = sCar[t][lane], v1 = sCar[t][lane + 64];
        float sum = v0 + v1;
        for (int m = 32; m; m >>= 1) sum += __shfl_xor(sum, m, 64);
        float mean = sum * (1.f / 128.f);
        float d0 = v0 - mean, d1 = v1 - mean;
        float vs = d0 * d0 + d1 * d1;
        for (int m = 32; m; m >>= 1) vs += __shfl_xor(vs, m, 64);
        float inv = rsqrtf(vs * (1.f / 128.f) + 1e-5f);
        sXn[t][lane]      = f2b(d0 * inv * g[lane]      + bb[lane]);
        sXn[t][lane + 64] = f2b(d1 * inv * g[lane + 64] + bb[lane + 64]);
      }
      __syncthreads();

      // ---- xproj GEMM: thread = column j of (40 x 256) output
      float acc[SEQL];
#pragma unroll
      for (int t = 0; t < SEQL; ++t) acc[t] = 0.f;
      for (int e0 = 0; e0 < EDIM; e0 += 4) {
        float wv0 = wx[(e0 + 0) * 256 + tid];
        float wv1 = wx[(e0 + 1) * 256 + tid];
        float wv2 = wx[(e0 + 2) * 256 + tid];
        float wv3 = wx[(e0 + 3) * 256 + tid];
#pragma unroll
        for (int t = 0; t < SEQL; ++t) {
          float x0, x1, x2, x3;
          ld4(&sXn[t][e0], x0, x1, x2, x3);   // broadcast read
          acc[t] = fmaf(x0, wv0, fmaf(x1, wv1, fmaf(x2, wv2, fmaf(x3, wv3, acc[t]))));
        }
      }

      // ---- split: threads <128 own delta channel -> s; >=128 own Bm -> prod
      if (tid < EDIM) {
        int e = tid;
        float bxv = bx[e];
        float Ar[NSTATE];
#pragma unroll
        for (int k = 0; k < NSTATE; ++k) Ar[k] = Ap[e * NSTATE + k];
#pragma unroll
        for (int t = 0; t < SEQL; ++t) {
          float xd = acc[t] + bxv;
          float sp = fmaxf(xd, 0.f) + log1pf(__expf(-fabsf(xd)));  // softplus
          float s = 0.f;
#pragma unroll
          for (int k = 0; k < NSTATE; ++k) s += __expf(sp * Ar[k]);
          sS[t][e] = f2b(s);
        }
      } else {
        int e = tid - EDIM;
        float bxv = bx[tid];
#pragma unroll
        for (int t = 0; t < SEQL; ++t)
          sH[t][e] = f2b(b2f(sXn[t][e]) * (acc[t] + bxv));
      }
      __syncthreads();

      // ---- cumsum over time (fwd: prefix, bwd: suffix), f32 running sum
      if (tid < EDIM) {
        int e = tid;
        float r = 0.f;
        if (dir == 0) {
          for (int t = 0; t < SEQL; ++t) { r += b2f(sH[t][e]); sH[t][e] = f2b(r); }
        } else {
          for (int t = SEQL - 1; t >= 0; --t) { r += b2f(sH[t][e]); sH[t][e] = f2b(r); }
        }
      }
      __syncthreads();

      // ---- o = h*s + xn*D (in place into sH)
      {
        int e = tid & 127, half = tid >> 7;
        float Dv = Dp[e];
#pragma unroll
        for (int tt = 0; tt < 20; ++tt) {
          int t = half * 20 + tt;
          sH[t][e] = f2b(b2f(sH[t][e]) * b2f(sS[t][e]) + b2f(sXn[t][e]) * Dv);
        }
      }
      __syncthreads();

      // ---- outproj GEMM + bias + residual -> sF (dir0) / sS (dir1)
      {
        int j = tid & 127, half = tid >> 7;
        float acc2[20];
#pragma unroll
        for (int tt = 0; tt < 20; ++tt) acc2[tt] = 0.f;
        for (int e0 = 0; e0 < EDIM; e0 += 4) {
          float wv0 = wo[(e0 + 0) * EDIM + j];
          float wv1 = wo[(e0 + 1) * EDIM + j];
          float wv2 = wo[(e0 + 2) * EDIM + j];
          float wv3 = wo[(e0 + 3) * EDIM + j];
#pragma unroll
          for (int tt = 0; tt < 20; ++tt) {
            int t = half * 20 + tt;
            float x0, x1, x2, x3;
            ld4(&sH[t][e0], x0, x1, x2, x3);
            acc2[tt] = fmaf(x0, wv0, fmaf(x1, wv1, fmaf(x2, wv2, fmaf(x3, wv3, acc2[tt]))));
          }
        }
        float bov = bo[j];
        unsigned short (*dst)[EDIM] = (dir == 0) ? sF : sS;
#pragma unroll
        for (int tt = 0; tt < 20; ++tt) {
          int t = half * 20 + tt;
          dst[t][j] = f2b(acc2[tt] + bov + sCar[t][j]);
        }
      }
      __syncthreads();
    } // dir

    // ---- merge: [f ; bk] (40 x 256) @ merge_w -> new carry
    {
      const float* mwl = mw  + l * 2 * EDIM * EDIM;
      const float* mbl = mbp + l * EDIM;
      int j = tid & 127, half = tid >> 7;
      float acc3[20];
#pragma unroll
      for (int tt = 0; tt < 20; ++tt) acc3[tt] = 0.f;
      for (int i0 = 0; i0 < 2 * EDIM; i0 += 4) {
        float wv0 = mwl[(i0 + 0) * EDIM + j];
        float wv1 = mwl[(i0 + 1) * EDIM + j];
        float wv2 = mwl[(i0 + 2) * EDIM + j];
        float wv3 = mwl[(i0 + 3) * EDIM + j];
        const bool inF = (i0 < EDIM);
#pragma unroll
        for (int tt = 0; tt < 20; ++tt) {
          int t = half * 20 + tt;
          const unsigned short* p = inF ? &sF[t][i0] : &sS[t][i0 - EDIM];
          float x0, x1, x2, x3;
          ld4(p, x0, x1, x2, x3);
          acc3[tt] = fmaf(x0, wv0, fmaf(x1, wv1, fmaf(x2, wv2, fmaf(x3, wv3, acc3[tt]))));
        }
      }
      __syncthreads();  // all reads of sF/sS done before carry overwrite hazards matter
      float mbv = mbl[j];
#pragma unroll
      for (int tt = 0; tt < 20; ++tt) {
        int t = half * 20 + tt;
        sCar[t][j] = acc3[tt] + mbv;
      }
    }
    __syncthreads();
  } // layers

  // ---- MLP head on token 0
  if (tid < 128) {
    float a = b1p[tid];
    for (int e = 0; e < EDIM; e += 4) {
      float4 hv = *(const float4*)&sCar[0][e];
      a = fmaf(hv.x, w1p[(e + 0) * 128 + tid],
          fmaf(hv.y, w1p[(e + 1) * 128 + tid],
          fmaf(hv.z, w1p[(e + 2) * 128 + tid],
          fmaf(hv.w, w1p[(e + 3) * 128 + tid], a))));
    }
    sCar[1][tid] = fmaxf(a, 0.f);
  }
  __syncthreads();
  if (tid < 64) {
    float a = b2p[tid];
    for (int i = 0; i < 128; ++i) a = fmaf(sCar[1][i], w2p[i * 64 + tid], a);
    a = fmaxf(a, 0.f);
    float v = a * w3p[tid];
    for (int m = 32; m; m >>= 1) v += __shfl_xor(v, m, 64);
    if (tid == 0) {
      float res = v + b3p[0];
      if (bf) ((unsigned short*)outp)[b] = f2b(res);
      else    ((float*)outp)[b] = res;
    }
  }
}

// ---------------- host launcher ----------------
extern "C" void kernel_launch(void* const* d_in, const int* in_sizes, int n_in,
                              void* d_out, int out_size, void* d_ws, size_t ws_size,
                              hipStream_t stream) {
  (void)n_in; (void)out_size; (void)ws_size;

  ConvArgs ca;
  int off = 0;
  for (int k = 0; k < 17; ++k) {        // inputs 2..18 (skip x, emb_table)
    ca.src[k] = d_in[k + 2];
    ca.off[k] = off;
    off += in_sizes[k + 2];
  }
  ca.off[17] = off;                     // total = 572289 floats (~2.3 MB)

  int*   flag = (int*)d_ws;
  float* W    = (float*)((char*)d_ws + 16);

  convert_kernel<<<dim3(1024), dim3(256), 0, stream>>>(ca, W, flag);
  mamba_kernel<<<dim3(2048), dim3(256), 0, stream>>>(
      (const int*)d_in[0], d_in[1], W, flag, d_out);
}

// Round 2
// 866.098 us; speedup vs baseline: 4.2089x; 4.2089x over previous
//
#include <hip/hip_runtime.h>

#define NFEAT   39
#define SEQL    40
#define EDIM    128
#define NSTATE  16
#define NLAYERS 4
#define VROWS   10001   // VOCAB + 1

typedef __attribute__((ext_vector_type(8))) short short8;   // 8 bf16 = 4 VGPRs
typedef __attribute__((ext_vector_type(4))) float f32x4;

// ---------------- bf16 helpers (raw ushort storage) ----------------
__device__ __forceinline__ float b2f(unsigned short u) {
  unsigned v = ((unsigned)u) << 16;
  return __builtin_bit_cast(float, v);
}
__device__ __forceinline__ unsigned short f2b(float f) {
  unsigned u = __builtin_bit_cast(unsigned, f);
  u += 0x7FFFu + ((u >> 16) & 1u);   // round-to-nearest-even
  return (unsigned short)(u >> 16);
}
__device__ __forceinline__ float ldin(const void* p, long i, int bf) {
  if (bf) return b2f(((const unsigned short*)p)[i]);
  return ((const float*)p)[i];
}

// ---------------- f32 arena offsets (floats) ----------------
#define OFF_CLS 0
#define OFF_LNG 128
#define OFF_LNB 1152
#define OFF_XB  2176
#define OFF_AT  4224      // A transposed: [pd][k][e]
#define OFF_D   20608
#define OFF_OB  21632
#define OFF_MB  22656
#define OFF_W1  23168
#define OFF_B1  39552
#define OFF_W2  39680
#define OFF_B2  47872
#define OFF_W3  47936
#define OFF_B3  48000
#define NF32    48001

#define NPK_XW  262144    // [8 pd][16 nt][4 kb][64 lane][8]
#define NPK_WO  131072    // [8 pd][8 nt][4 kb][64][8]
#define NPK_MW  131072    // [4 l][8 nt][8 kb][64][8]

struct SrcPtrs { const void* p[19]; };

// ---------------- convert/pack kernel ----------------
__global__ void convert_kernel(SrcPtrs sp, float* W, unsigned short* pkxw,
                               unsigned short* pkwo, unsigned short* pkmw,
                               int* flag) {
  unsigned w0 = *(const unsigned*)sp.p[3];              // ln_g first word
  int bf = (w0 != 0x3F800000u) ? 1 : 0;
  if (blockIdx.x == 0 && threadIdx.x == 0) *flag = bf;
  const int T0 = NF32;
  const int T1 = T0 + NPK_XW;
  const int T2 = T1 + NPK_WO;
  const int T3 = T2 + NPK_MW;
  for (int i = blockIdx.x * blockDim.x + threadIdx.x; i < T3;
       i += gridDim.x * blockDim.x) {
    if (i < T0) {
      const void* s; int li;
      if      (i < OFF_LNG) { s = sp.p[2];  li = i - OFF_CLS; }
      else if (i < OFF_LNB) { s = sp.p[3];  li = i - OFF_LNG; }
      else if (i < OFF_XB)  { s = sp.p[4];  li = i - OFF_LNB; }
      else if (i < OFF_AT)  { s = sp.p[6];  li = i - OFF_XB; }
      else if (i < OFF_D)   { s = sp.p[7];  int o = i - OFF_AT;
                              int e = o & 127, k = (o >> 7) & 15, pd = o >> 11;
                              li = (pd * 128 + e) * 16 + k; }
      else if (i < OFF_OB)  { s = sp.p[8];  li = i - OFF_D; }
      else if (i < OFF_MB)  { s = sp.p[10]; li = i - OFF_OB; }
      else if (i < OFF_W1)  { s = sp.p[12]; li = i - OFF_MB; }
      else if (i < OFF_B1)  { s = sp.p[13]; li = i - OFF_W1; }
      else if (i < OFF_W2)  { s = sp.p[14]; li = i - OFF_B1; }
      else if (i < OFF_B2)  { s = sp.p[15]; li = i - OFF_W2; }
      else if (i < OFF_W3)  { s = sp.p[16]; li = i - OFF_B2; }
      else if (i < OFF_B3)  { s = sp.p[17]; li = i - OFF_W3; }
      else                  { s = sp.p[18]; li = i - OFF_B3; }
      W[i] = bf ? b2f(((const unsigned short*)s)[li]) : ((const float*)s)[li];
    } else if (i < T1) {
      int o = i - T0;
      int j = o & 7, lane = (o >> 3) & 63, kb = (o >> 9) & 3;
      int nt = (o >> 11) & 15, pd = o >> 15;
      int k = kb * 32 + (lane >> 4) * 8 + j;
      int n = nt * 16 + (lane & 15);
      float v = bf ? b2f(((const unsigned short*)sp.p[5])[(pd * 128 + k) * 256 + n])
                   : ((const float*)sp.p[5])[(pd * 128 + k) * 256 + n];
      pkxw[o] = f2b(v);
    } else if (i < T2) {
      int o = i - T1;
      int j = o & 7, lane = (o >> 3) & 63, kb = (o >> 9) & 3;
      int nt = (o >> 11) & 7, pd = o >> 14;
      int k = kb * 32 + (lane >> 4) * 8 + j;
      int n = nt * 16 + (lane & 15);
      float v = bf ? b2f(((const unsigned short*)sp.p[9])[(pd * 128 + k) * 128 + n])
                   : ((const float*)sp.p[9])[(pd * 128 + k) * 128 + n];
      pkwo[o] = f2b(v);
    } else {
      int o = i - T2;
      int j = o & 7, lane = (o >> 3) & 63, kb = (o >> 9) & 7;
      int nt = (o >> 12) & 7, l = o >> 15;
      int k = kb * 32 + (lane >> 4) * 8 + j;
      int n = nt * 16 + (lane & 15);
      float v = bf ? b2f(((const unsigned short*)sp.p[11])[(l * 256 + k) * 128 + n])
                   : ((const float*)sp.p[11])[(l * 256 + k) * 128 + n];
      pkmw[o] = f2b(v);
    }
  }
}

// ---------------- main kernel: one block (4 waves) per sample ----------------
// LDS strides: sCar 132 f32 (+4 pad), bf16 tiles 136 (+8 pad, keeps rows 16B
// aligned so A-frag ds_read_b128 is single-instr and bank-balanced).
__global__ __launch_bounds__(256, 2)
void mamba_kernel(const int* __restrict__ x, const void* __restrict__ emb,
                  const float* __restrict__ W,
                  const unsigned short* __restrict__ pkxw,
                  const unsigned short* __restrict__ pkwo,
                  const unsigned short* __restrict__ pkmw,
                  const int* __restrict__ flagp, void* __restrict__ outp) {
  __shared__ __align__(16) float          sCar[SEQL * 132];   // 20.6 KB residual (f32)
  __shared__ __align__(16) unsigned short sXB [48 * 136];     // xn; aliased as bk
  __shared__ __align__(16) unsigned short sHO [48 * 136];     // prod/h/o
  __shared__ __align__(16) unsigned short sF  [48 * 136];     // f

  const int b    = blockIdx.x;
  const int tid  = threadIdx.x;
  const int w    = tid >> 6;
  const int lane = tid & 63;
  const int q    = lane >> 4;
  const int li   = lane & 15;
  const int bf   = *flagp;

  // ---- build seq into sCar: cls at t=0, embedding gather (idx 0 -> 0)
  for (int i = tid; i < SEQL * EDIM; i += 256) {
    int t = i >> 7, e = i & 127;
    float v;
    if (t == 0) v = W[OFF_CLS + e];
    else {
      int f = t - 1;
      int idx = x[b * NFEAT + f];
      v = (idx == 0) ? 0.f : ldin(emb, ((long)f * VROWS + idx) * EDIM + e, bf);
    }
    sCar[t * 132 + e] = v;
  }
  __syncthreads();

  for (int l = 0; l < NLAYERS; ++l) {
    for (int dir = 0; dir < 2; ++dir) {
      const int pd = l * 2 + dir;
      const float* g  = W + OFF_LNG + pd * EDIM;
      const float* bb = W + OFF_LNB + pd * EDIM;
      const float* bx = W + OFF_XB + pd * 256;
      const float* AT = W + OFF_AT + pd * 16 * 128;
      const float* Dp = W + OFF_D  + pd * EDIM;
      const float* bo = W + OFF_OB + pd * EDIM;

      // ---- LayerNorm: wave per token
      for (int t = w; t < SEQL; t += 4) {
        float v0 = sCar[t * 132 + lane], v1 = sCar[t * 132 + lane + 64];
        float sum = v0 + v1;
        for (int m = 32; m; m >>= 1) sum += __shfl_xor(sum, m, 64);
        float mean = sum * (1.f / 128.f);
        float d0 = v0 - mean, d1 = v1 - mean;
        float vs = d0 * d0 + d1 * d1;
        for (int m = 32; m; m >>= 1) vs += __shfl_xor(vs, m, 64);
        float inv = rsqrtf(vs * (1.f / 128.f) + 1e-5f);
        sXB[t * 136 + lane]      = f2b(d0 * inv * g[lane]      + bb[lane]);
        sXB[t * 136 + lane + 64] = f2b(d1 * inv * g[lane + 64] + bb[lane + 64]);
      }
      __syncthreads();

      // ---- xproj (MFMA) + register-resident SSM middle
      for (int cti = 0; cti < 2; ++cti) {
        const int ct = w + cti * 4;
        const int e  = ct * 16 + li;          // this lane's channel
        short8 Bd[4], Bb4[4];
#pragma unroll
        for (int kb = 0; kb < 4; ++kb) {
          Bd[kb]  = *(const short8*)(pkxw + (((pd * 16 + ct)     * 4 + kb) * 64 + lane) * 8);
          Bb4[kb] = *(const short8*)(pkxw + (((pd * 16 + ct + 8) * 4 + kb) * 64 + lane) * 8);
        }
        float Ar[16];
#pragma unroll
        for (int k = 0; k < 16; ++k) Ar[k] = AT[k * 128 + e];
        float bxd = bx[e], bxb = bx[128 + e], Dv = Dp[e];
        float sv[3][4], xnv[3][4], pv[3][4];
#pragma unroll
        for (int m = 0; m < 3; ++m) {
          f32x4 aD = {0.f, 0.f, 0.f, 0.f}, aB = {0.f, 0.f, 0.f, 0.f};
#pragma unroll
          for (int kb = 0; kb < 4; ++kb) {
            const short8 afr = *(const short8*)(sXB + (m * 16 + li) * 136 + kb * 32 + q * 8);
            aD = __builtin_amdgcn_mfma_f32_16x16x32_bf16(afr, Bd[kb],  aD, 0, 0, 0);
            aB = __builtin_amdgcn_mfma_f32_16x16x32_bf16(afr, Bb4[kb], aB, 0, 0, 0);
          }
#pragma unroll
          for (int r = 0; r < 4; ++r) {
            int t = m * 16 + q * 4 + r;
            float xd  = aD[r] + bxd;
            float spv = fmaxf(xd, 0.f) + __logf(1.f + __expf(-fabsf(xd)));
            float s = 0.f;
#pragma unroll
            for (int k = 0; k < 16; ++k) s += __expf(spv * Ar[k]);
            sv[m][r] = s;
            float xn = b2f(sXB[t * 136 + e]);
            xnv[m][r] = xn;
            float p = xn * (aB[r] + bxb);
            pv[m][r] = (t < SEQL) ? p : 0.f;       // zero pad rows (scan safety)
          }
        }
        // ---- in-register cumsum over t (prefix fwd / suffix bwd)
        if (dir == 0) {
          float base = 0.f;
#pragma unroll
          for (int m = 0; m < 3; ++m) {
            float p0 = pv[m][0], p1 = p0 + pv[m][1];
            float p2 = p1 + pv[m][2], p3 = p2 + pv[m][3];
            float c  = p3;
            float e1 = __shfl_up(c, 16, 64);
            float e2 = __shfl_up(c, 32, 64);
            float e3 = __shfl_up(c, 48, 64);
            float ex = (q >= 1 ? e1 : 0.f) + (q >= 2 ? e2 : 0.f) + (q >= 3 ? e3 : 0.f);
            float tot = __shfl(ex + c, 48 + li, 64);
            pv[m][0] = base + ex + p0; pv[m][1] = base + ex + p1;
            pv[m][2] = base + ex + p2; pv[m][3] = base + ex + p3;
            base += tot;
          }
        } else {
          float base = 0.f;
#pragma unroll
          for (int m = 2; m >= 0; --m) {
            float p3 = pv[m][3], p2 = p3 + pv[m][2];
            float p1 = p2 + pv[m][1], p0 = p1 + pv[m][0];
            float c  = p0;
            float e1 = __shfl_down(c, 16, 64);
            float e2 = __shfl_down(c, 32, 64);
            float e3 = __shfl_down(c, 48, 64);
            float ex = (q <= 2 ? e1 : 0.f) + (q <= 1 ? e2 : 0.f) + (q <= 0 ? e3 : 0.f);
            float tot = __shfl(ex + c, li, 64);
            pv[m][0] = base + ex + p0; pv[m][1] = base + ex + p1;
            pv[m][2] = base + ex + p2; pv[m][3] = base + ex + p3;
            base += tot;
          }
        }
        // ---- o = h*s + xn*D -> sHO
#pragma unroll
        for (int m = 0; m < 3; ++m)
#pragma unroll
          for (int r = 0; r < 4; ++r) {
            int t = m * 16 + q * 4 + r;
            sHO[t * 136 + e] = f2b(pv[m][r] * sv[m][r] + xnv[m][r] * Dv);
          }
      }
      __syncthreads();

      // ---- outproj (MFMA) + bias + residual -> sF (dir0) / sXB-as-bk (dir1)
      {
        unsigned short* dst = dir ? sXB : sF;
        for (int nti = 0; nti < 2; ++nti) {
          const int nt = w + nti * 4;
          const int n  = nt * 16 + li;
          short8 Bf[4];
#pragma unroll
          for (int kb = 0; kb < 4; ++kb)
            Bf[kb] = *(const short8*)(pkwo + (((pd * 8 + nt) * 4 + kb) * 64 + lane) * 8);
          float bov = bo[n];
#pragma unroll
          for (int m = 0; m < 3; ++m) {
            f32x4 ac = {0.f, 0.f, 0.f, 0.f};
#pragma unroll
            for (int kb = 0; kb < 4; ++kb) {
              const short8 afr = *(const short8*)(sHO + (m * 16 + li) * 136 + kb * 32 + q * 8);
              ac = __builtin_amdgcn_mfma_f32_16x16x32_bf16(afr, Bf[kb], ac, 0, 0, 0);
            }
#pragma unroll
            for (int r = 0; r < 4; ++r) {
              int t = m * 16 + q * 4 + r;
              if (t < SEQL)
                dst[t * 136 + n] = f2b(ac[r] + bov + sCar[t * 132 + n]);
            }
          }
        }
      }
      __syncthreads();
    } // dir

    // ---- merge (MFMA, K=256: sF then sXB-as-bk) -> sCar
    {
      const float* mb = W + OFF_MB + l * EDIM;
      for (int nti = 0; nti < 2; ++nti) {
        const int nt = w + nti * 4;
        const int n  = nt * 16 + li;
        short8 Bf[8];
#pragma unroll
        for (int kb = 0; kb < 8; ++kb)
          Bf[kb] = *(const short8*)(pkmw + (((l * 8 + nt) * 8 + kb) * 64 + lane) * 8);
        float mbv = mb[n];
#pragma unroll
        for (int m = 0; m < 3; ++m) {
          f32x4 ac = {0.f, 0.f, 0.f, 0.f};
#pragma unroll
          for (int kb = 0; kb < 4; ++kb) {
            const short8 afr = *(const short8*)(sF + (m * 16 + li) * 136 + kb * 32 + q * 8);
            ac = __builtin_amdgcn_mfma_f32_16x16x32_bf16(afr, Bf[kb], ac, 0, 0, 0);
          }
#pragma unroll
          for (int kb = 4; kb < 8; ++kb) {
            const short8 afr = *(const short8*)(sXB + (m * 16 + li) * 136 + (kb - 4) * 32 + q * 8);
            ac = __builtin_amdgcn_mfma_f32_16x16x32_bf16(afr, Bf[kb], ac, 0, 0, 0);
          }
#pragma unroll
          for (int r = 0; r < 4; ++r) {
            int t = m * 16 + q * 4 + r;
            if (t < SEQL) sCar[t * 132 + n] = ac[r] + mbv;
          }
        }
      }
    }
    __syncthreads();
  } // layers

  // ---- MLP head on token 0
  if (tid < 128) {
    float a = W[OFF_B1 + tid];
    const float* w1p = W + OFF_W1;
    for (int e = 0; e < EDIM; e += 4) {
      float4 hv = *(const float4*)&sCar[e];
      a = fmaf(hv.x, w1p[(e + 0) * 128 + tid],
          fmaf(hv.y, w1p[(e + 1) * 128 + tid],
          fmaf(hv.z, w1p[(e + 2) * 128 + tid],
          fmaf(hv.w, w1p[(e + 3) * 128 + tid], a))));
    }
    sCar[132 + tid] = fmaxf(a, 0.f);
  }
  __syncthreads();
  if (tid < 64) {
    float a = W[OFF_B2 + tid];
    const float* w2p = W + OFF_W2;
    for (int i = 0; i < 128; ++i) a = fmaf(sCar[132 + i], w2p[i * 64 + tid], a);
    a = fmaxf(a, 0.f);
    float v = a * W[OFF_W3 + tid];
    for (int m = 32; m; m >>= 1) v += __shfl_xor(v, m, 64);
    if (tid == 0) {
      float res = v + W[OFF_B3];
      if (bf) ((unsigned short*)outp)[b] = f2b(res);
      else    ((float*)outp)[b] = res;
    }
  }
}

// ---------------- host launcher ----------------
extern "C" void kernel_launch(void* const* d_in, const int* in_sizes, int n_in,
                              void* d_out, int out_size, void* d_ws, size_t ws_size,
                              hipStream_t stream) {
  (void)in_sizes; (void)n_in; (void)out_size; (void)ws_size;

  SrcPtrs sp;
  for (int k = 0; k < 19; ++k) sp.p[k] = d_in[k];

  int*            flag = (int*)d_ws;
  float*          Wf   = (float*)((char*)d_ws + 256);
  unsigned short* pkxw = (unsigned short*)((char*)d_ws + 256 + 200704);
  unsigned short* pkwo = pkxw + NPK_XW;
  unsigned short* pkmw = pkwo + NPK_WO;

  convert_kernel<<<dim3(512), dim3(256), 0, stream>>>(sp, Wf, pkxw, pkwo, pkmw, flag);
  mamba_kernel<<<dim3(2048), dim3(256), 0, stream>>>(
      (const int*)d_in[0], d_in[1], Wf, pkxw, pkwo, pkmw, flag, d_out);
}